// Round 1
// baseline (512.934 us; speedup 1.0000x reference)
//
#include <hip/hip_runtime.h>
#include <math.h>

#define KD 5
#define NN 60000
#define EE 360000
#define NP1 30000
#define EE2 180000
#define NP2 15000
#define GG 60

// ---------- helpers ----------

__device__ __forceinline__ unsigned fkey(float f) {
    unsigned u = __float_as_uint(f);
    return (u & 0x80000000u) ? ~u : (u | 0x80000000u);
}
__device__ __forceinline__ float fkey_inv(unsigned k) {
    unsigned u = (k & 0x80000000u) ? (k ^ 0x80000000u) : ~k;
    return __uint_as_float(u);
}

__device__ __forceinline__ void spline_basis(float p0, float p1, int* idx, float* w) {
    float v0 = p0 * 4.0f, v1 = p1 * 4.0f;
    float fl0 = floorf(v0), fl1 = floorf(v1);
    int i0 = min(max((int)fl0, 0), KD - 1);
    int i1 = min(max((int)fl1, 0), KD - 1);
    float fr0 = v0 - fl0, fr1 = v1 - fl1;
    int c = 0;
#pragma unroll
    for (int s0 = 0; s0 < 2; ++s0) {
#pragma unroll
        for (int s1 = 0; s1 < 2; ++s1) {
            int ix = min(i0 + s0, KD - 1);
            int iy = min(i1 + s1, KD - 1);
            float w0 = s0 ? fr0 : 1.0f - fr0;
            float w1 = s1 ? fr1 : 1.0f - fr1;
            idx[c] = ix + KD * iy;
            w[c] = w0 * w1;
            ++c;
        }
    }
}

__device__ __forceinline__ float elu1(float v) {
    return v > 0.0f ? v : expm1f(v);
}

// ---------- conv1 ----------

__global__ void conv1_edge(const float* __restrict__ x, const float* __restrict__ ea,
                           const int* __restrict__ ei, const float* __restrict__ W1,
                           float* __restrict__ agg1, float* __restrict__ cnt1) {
    int gid = blockIdx.x * blockDim.x + threadIdx.x;
    if (gid >= EE * 32) return;
    int e = gid >> 5, f = gid & 31;
    int src = ei[e], dst = ei[EE + e];
    int idx[4]; float w[4];
    spline_basis(ea[2 * e], ea[2 * e + 1], idx, w);
    float coeff = 0.0f;
#pragma unroll
    for (int k = 0; k < 4; ++k) coeff += w[k] * W1[idx[k] * 32 + f];
    atomicAdd(&agg1[dst * 32 + f], x[src] * coeff);
    if (f == 0) atomicAdd(&cnt1[dst], 1.0f);
}

__global__ void conv1_fin(const float* __restrict__ x, const float* __restrict__ root1,
                          const float* __restrict__ bias1, const float* __restrict__ cnt1,
                          float* __restrict__ agg1) {
    int gid = blockIdx.x * blockDim.x + threadIdx.x;
    if (gid >= NN * 32) return;
    int n = gid >> 5, f = gid & 31;
    float v = agg1[gid] / fmaxf(cnt1[n], 1.0f) + x[n] * root1[f] + bias1[f];
    agg1[gid] = elu1(v);
}

// ---------- pool1 ----------

__global__ void pool1(const float* __restrict__ h, const float* __restrict__ pos,
                      const int* __restrict__ batch, const int* __restrict__ cl1,
                      unsigned* __restrict__ x1key, int* __restrict__ ccnt1,
                      float* __restrict__ pos1, int* __restrict__ batch1) {
    int gid = blockIdx.x * blockDim.x + threadIdx.x;
    if (gid >= NN * 32) return;
    int n = gid >> 5, f = gid & 31;
    int c = cl1[n];
    atomicMax(&x1key[c * 32 + f], fkey(h[gid]));
    if (f == 0) {
        atomicAdd(&ccnt1[c], 1);
        atomicAdd(&pos1[c * 2], pos[n * 2]);
        atomicAdd(&pos1[c * 2 + 1], pos[n * 2 + 1]);
        atomicMax(&batch1[c], batch[n]);
    }
}

__global__ void pool1_fin(unsigned* __restrict__ x1key, const int* __restrict__ ccnt1,
                          float* __restrict__ pos1) {
    int gid = blockIdx.x * blockDim.x + threadIdx.x;
    if (gid >= NP1 * 32) return;
    int c = gid >> 5, f = gid & 31;
    int cnt = ccnt1[c];
    float v = cnt > 0 ? fkey_inv(x1key[gid]) : 0.0f;
    ((float*)x1key)[gid] = v;
    if (f < 2) pos1[c * 2 + f] = pos1[c * 2 + f] / fmaxf((float)cnt, 1.0f);
}

// ---------- cartesian ----------

__global__ void cart_k(const float* __restrict__ pos1, const int* __restrict__ ei2,
                       float* __restrict__ attr2, unsigned* __restrict__ scaleb) {
    int e = blockIdx.x * blockDim.x + threadIdx.x;
    float m = 0.0f;
    if (e < EE2) {
        int s = ei2[e], d = ei2[EE2 + e];
        float c0 = pos1[d * 2] - pos1[s * 2];
        float c1 = pos1[d * 2 + 1] - pos1[s * 2 + 1];
        attr2[e * 2] = c0;
        attr2[e * 2 + 1] = c1;
        m = fmaxf(fabsf(c0), fabsf(c1));
    }
#pragma unroll
    for (int off = 32; off > 0; off >>= 1) m = fmaxf(m, __shfl_down(m, off));
    if ((threadIdx.x & 63) == 0) atomicMax(scaleb, __float_as_uint(m));
}

__global__ void attr2_fin(float* __restrict__ attr2, const unsigned* __restrict__ scaleb) {
    int gid = blockIdx.x * blockDim.x + threadIdx.x;
    if (gid >= EE2 * 2) return;
    float s = fmaxf(__uint_as_float(*scaleb), 1e-12f);
    attr2[gid] = attr2[gid] / (2.0f * s) + 0.5f;
}

// ---------- conv2 ----------

__global__ void conv2_edge(const float* __restrict__ x1, const float* __restrict__ attr2,
                           const int* __restrict__ ei2, const float* __restrict__ W2,
                           float* __restrict__ agg2, float* __restrict__ cnt2) {
    int gid = blockIdx.x * blockDim.x + threadIdx.x;
    if (gid >= EE2 * 64) return;
    int e = gid >> 6, f = gid & 63;
    int src = ei2[e], dst = ei2[EE2 + e];
    int idx[4]; float w[4];
    spline_basis(attr2[2 * e], attr2[2 * e + 1], idx, w);
    float xv[32];
    const float* xs = x1 + src * 32;
#pragma unroll
    for (int i = 0; i < 32; ++i) xv[i] = xs[i];
    float msg = 0.0f;
#pragma unroll
    for (int k = 0; k < 4; ++k) {
        const float* Wk = W2 + idx[k] * (32 * 64) + f;
        float acc = 0.0f;
#pragma unroll
        for (int fin = 0; fin < 32; ++fin) acc += xv[fin] * Wk[fin * 64];
        msg += w[k] * acc;
    }
    atomicAdd(&agg2[dst * 64 + f], msg);
    if (f == 0) atomicAdd(&cnt2[dst], 1.0f);
}

__global__ void conv2_fin(const float* __restrict__ x1, const float* __restrict__ root2,
                          const float* __restrict__ bias2, const float* __restrict__ cnt2,
                          float* __restrict__ agg2) {
    int gid = blockIdx.x * blockDim.x + threadIdx.x;
    if (gid >= NP1 * 64) return;
    int n = gid >> 6, f = gid & 63;
    float r = 0.0f;
    const float* xs = x1 + n * 32;
#pragma unroll
    for (int i = 0; i < 32; ++i) r += xs[i] * root2[i * 64 + f];
    float v = agg2[gid] / fmaxf(cnt2[n], 1.0f) + r + bias2[f];
    agg2[gid] = elu1(v);
}

// ---------- pool2 + global pool ----------

__global__ void pool2(const float* __restrict__ h2, const int* __restrict__ batch1,
                      const int* __restrict__ cl2, unsigned* __restrict__ x2key,
                      int* __restrict__ ccnt2, int* __restrict__ batch2) {
    int gid = blockIdx.x * blockDim.x + threadIdx.x;
    if (gid >= NP1 * 64) return;
    int n = gid >> 6, f = gid & 63;
    int c = cl2[n];
    atomicMax(&x2key[c * 64 + f], fkey(h2[gid]));
    if (f == 0) {
        atomicAdd(&ccnt2[c], 1);
        atomicMax(&batch2[c], batch1[n]);
    }
}

__global__ void pool2_fin(const unsigned* __restrict__ x2key, const int* __restrict__ ccnt2,
                          const int* __restrict__ batch2, float* __restrict__ gsum,
                          float* __restrict__ gcnt) {
    int gid = blockIdx.x * blockDim.x + threadIdx.x;
    if (gid >= NP2 * 64) return;
    int c = gid >> 6, f = gid & 63;
    int cnt = ccnt2[c];
    float v = cnt > 0 ? fkey_inv(x2key[gid]) : 0.0f;
    int g = batch2[c];
    atomicAdd(&gsum[g * 64 + f], v);
    if (f == 0) atomicAdd(&gcnt[g], 1.0f);
}

// ---------- head ----------

__global__ void head_k(const float* __restrict__ gsum, const float* __restrict__ gcnt,
                       const float* __restrict__ fc1w, const float* __restrict__ fc1b,
                       const float* __restrict__ fc2w, const float* __restrict__ fc2b,
                       float* __restrict__ out) {
    int g = blockIdx.x;
    int t = threadIdx.x;
    __shared__ float gm[64];
    __shared__ float h3[128];
    __shared__ float lg[3];
    if (t < 64) gm[t] = gsum[g * 64 + t] / fmaxf(gcnt[g], 1.0f);
    __syncthreads();
    float a = fc1b[t];
#pragma unroll
    for (int i = 0; i < 64; ++i) a += gm[i] * fc1w[i * 128 + t];
    h3[t] = elu1(a);
    __syncthreads();
    if (t < 3) {
        float a2 = fc2b[t];
#pragma unroll
        for (int i = 0; i < 128; ++i) a2 += h3[i] * fc2w[i * 3 + t];
        lg[t] = a2;
    }
    __syncthreads();
    if (t == 0) {
        float m = fmaxf(lg[0], fmaxf(lg[1], lg[2]));
        float s = expf(lg[0] - m) + expf(lg[1] - m) + expf(lg[2] - m);
        float lse = m + logf(s);
        out[g * 3 + 0] = lg[0] - lse;
        out[g * 3 + 1] = lg[1] - lse;
        out[g * 3 + 2] = lg[2] - lse;
    }
}

// ---------- launcher ----------

extern "C" void kernel_launch(void* const* d_in, const int* in_sizes, int n_in,
                              void* d_out, int out_size, void* d_ws, size_t ws_size,
                              hipStream_t stream) {
    const float* x     = (const float*)d_in[0];
    const float* pos   = (const float*)d_in[1];
    const float* eattr = (const float*)d_in[2];
    const int*   ei    = (const int*)d_in[3];
    const int*   batch = (const int*)d_in[4];
    const int*   cl1   = (const int*)d_in[5];
    const int*   ei2   = (const int*)d_in[6];
    const int*   cl2   = (const int*)d_in[7];
    const float* W1    = (const float*)d_in[8];
    const float* root1 = (const float*)d_in[9];
    const float* bias1 = (const float*)d_in[10];
    const float* W2    = (const float*)d_in[11];
    const float* root2 = (const float*)d_in[12];
    const float* bias2 = (const float*)d_in[13];
    const float* fc1w  = (const float*)d_in[14];
    const float* fc1b  = (const float*)d_in[15];
    const float* fc2w  = (const float*)d_in[16];
    const float* fc2b  = (const float*)d_in[17];
    float* out = (float*)d_out;

    char* p = (char*)d_ws;
    auto carve = [&](size_t bytes) {
        char* r = p;
        p += (bytes + 255) & ~(size_t)255;
        return r;
    };
    float*    agg1   = (float*)carve((size_t)NN * 32 * 4);
    float*    cnt1   = (float*)carve((size_t)NN * 4);
    unsigned* x1key  = (unsigned*)carve((size_t)NP1 * 32 * 4);  // becomes float x1 in-place
    int*      ccnt1  = (int*)carve((size_t)NP1 * 4);
    float*    pos1   = (float*)carve((size_t)NP1 * 2 * 4);
    int*      batch1 = (int*)carve((size_t)NP1 * 4);
    unsigned* scaleb = (unsigned*)carve(4);
    float*    attr2  = (float*)carve((size_t)EE2 * 2 * 4);
    float*    agg2   = (float*)carve((size_t)NP1 * 64 * 4);
    float*    cnt2   = (float*)carve((size_t)NP1 * 4);
    unsigned* x2key  = (unsigned*)carve((size_t)NP2 * 64 * 4);
    int*      ccnt2  = (int*)carve((size_t)NP2 * 4);
    int*      batch2 = (int*)carve((size_t)NP2 * 4);
    float*    gsum   = (float*)carve((size_t)GG * 64 * 4);
    float*    gcnt   = (float*)carve((size_t)GG * 4);
    size_t used = (size_t)(p - (char*)d_ws);
    hipMemsetAsync(d_ws, 0, used, stream);

    const int B = 256;
    conv1_edge<<<(EE * 32 + B - 1) / B, B, 0, stream>>>(x, eattr, ei, W1, agg1, cnt1);
    conv1_fin<<<(NN * 32 + B - 1) / B, B, 0, stream>>>(x, root1, bias1, cnt1, agg1);
    pool1<<<(NN * 32 + B - 1) / B, B, 0, stream>>>(agg1, pos, batch, cl1, x1key, ccnt1, pos1, batch1);
    pool1_fin<<<(NP1 * 32 + B - 1) / B, B, 0, stream>>>(x1key, ccnt1, pos1);
    cart_k<<<(EE2 + B - 1) / B, B, 0, stream>>>(pos1, ei2, attr2, scaleb);
    attr2_fin<<<(EE2 * 2 + B - 1) / B, B, 0, stream>>>(attr2, scaleb);
    conv2_edge<<<(EE2 * 64 + B - 1) / B, B, 0, stream>>>((const float*)x1key, attr2, ei2, W2, agg2, cnt2);
    conv2_fin<<<(NP1 * 64 + B - 1) / B, B, 0, stream>>>((const float*)x1key, root2, bias2, cnt2, agg2);
    pool2<<<(NP1 * 64 + B - 1) / B, B, 0, stream>>>(agg2, batch1, cl2, x2key, ccnt2, batch2);
    pool2_fin<<<(NP2 * 64 + B - 1) / B, B, 0, stream>>>(x2key, ccnt2, batch2, gsum, gcnt);
    head_k<<<GG, 128, 0, stream>>>(gsum, gcnt, fc1w, fc1b, fc2w, fc2b, out);
}

// Round 2
// 368.118 us; speedup vs baseline: 1.3934x; 1.3934x over previous
//
#include <hip/hip_runtime.h>
#include <math.h>

#define KD 5
#define NN 60000
#define EE 360000
#define NP1 30000
#define EE2 180000
#define NP2 15000
#define GG 60

// conv2 tiling
#define FH 16      // fout quarter width
#define NBLK 512   // edge blocks per quarter

// ---------- helpers ----------

__device__ __forceinline__ unsigned fkey(float f) {
    unsigned u = __float_as_uint(f);
    return (u & 0x80000000u) ? ~u : (u | 0x80000000u);
}
__device__ __forceinline__ float fkey_inv(unsigned k) {
    unsigned u = (k & 0x80000000u) ? (k ^ 0x80000000u) : ~k;
    return __uint_as_float(u);
}

__device__ __forceinline__ void spline_basis(float p0, float p1, int* idx, float* w) {
    float v0 = p0 * 4.0f, v1 = p1 * 4.0f;
    float fl0 = floorf(v0), fl1 = floorf(v1);
    int i0 = min(max((int)fl0, 0), KD - 1);
    int i1 = min(max((int)fl1, 0), KD - 1);
    float fr0 = v0 - fl0, fr1 = v1 - fl1;
    int c = 0;
#pragma unroll
    for (int s0 = 0; s0 < 2; ++s0) {
#pragma unroll
        for (int s1 = 0; s1 < 2; ++s1) {
            int ix = min(i0 + s0, KD - 1);
            int iy = min(i1 + s1, KD - 1);
            float w0 = s0 ? fr0 : 1.0f - fr0;
            float w1 = s1 ? fr1 : 1.0f - fr1;
            idx[c] = ix + KD * iy;
            w[c] = w0 * w1;
            ++c;
        }
    }
}

__device__ __forceinline__ float elu1(float v) {
    return v > 0.0f ? v : expm1f(v);
}

// ---------- conv1 ----------

__global__ void conv1_edge(const float* __restrict__ x, const float* __restrict__ ea,
                           const int* __restrict__ ei, const float* __restrict__ W1,
                           float* __restrict__ agg1, float* __restrict__ cnt1) {
    int gid = blockIdx.x * blockDim.x + threadIdx.x;
    if (gid >= EE * 32) return;
    int e = gid >> 5, f = gid & 31;
    int src = ei[e], dst = ei[EE + e];
    int idx[4]; float w[4];
    spline_basis(ea[2 * e], ea[2 * e + 1], idx, w);
    float coeff = 0.0f;
#pragma unroll
    for (int k = 0; k < 4; ++k) coeff += w[k] * W1[idx[k] * 32 + f];
    atomicAdd(&agg1[dst * 32 + f], x[src] * coeff);
    if (f == 0) atomicAdd(&cnt1[dst], 1.0f);
}

__global__ void conv1_fin(const float* __restrict__ x, const float* __restrict__ root1,
                          const float* __restrict__ bias1, const float* __restrict__ cnt1,
                          float* __restrict__ agg1) {
    int gid = blockIdx.x * blockDim.x + threadIdx.x;
    if (gid >= NN * 32) return;
    int n = gid >> 5, f = gid & 31;
    float v = agg1[gid] / fmaxf(cnt1[n], 1.0f) + x[n] * root1[f] + bias1[f];
    agg1[gid] = elu1(v);
}

// ---------- pool1 ----------

__global__ void pool1(const float* __restrict__ h, const float* __restrict__ pos,
                      const int* __restrict__ batch, const int* __restrict__ cl1,
                      unsigned* __restrict__ x1key, int* __restrict__ ccnt1,
                      float* __restrict__ pos1, int* __restrict__ batch1) {
    int gid = blockIdx.x * blockDim.x + threadIdx.x;
    if (gid >= NN * 32) return;
    int n = gid >> 5, f = gid & 31;
    int c = cl1[n];
    atomicMax(&x1key[c * 32 + f], fkey(h[gid]));
    if (f == 0) {
        atomicAdd(&ccnt1[c], 1);
        atomicAdd(&pos1[c * 2], pos[n * 2]);
        atomicAdd(&pos1[c * 2 + 1], pos[n * 2 + 1]);
        atomicMax(&batch1[c], batch[n]);
    }
}

__global__ void pool1_fin(unsigned* __restrict__ x1key, const int* __restrict__ ccnt1,
                          float* __restrict__ pos1) {
    int gid = blockIdx.x * blockDim.x + threadIdx.x;
    if (gid >= NP1 * 32) return;
    int c = gid >> 5, f = gid & 31;
    int cnt = ccnt1[c];
    float v = cnt > 0 ? fkey_inv(x1key[gid]) : 0.0f;
    ((float*)x1key)[gid] = v;
    if (f < 2) pos1[c * 2 + f] = pos1[c * 2 + f] / fmaxf((float)cnt, 1.0f);
}

// ---------- cartesian ----------

__global__ void cart_k(const float* __restrict__ pos1, const int* __restrict__ ei2,
                       float* __restrict__ attr2, unsigned* __restrict__ scaleb) {
    int e = blockIdx.x * blockDim.x + threadIdx.x;
    float m = 0.0f;
    if (e < EE2) {
        int s = ei2[e], d = ei2[EE2 + e];
        float c0 = pos1[d * 2] - pos1[s * 2];
        float c1 = pos1[d * 2 + 1] - pos1[s * 2 + 1];
        attr2[e * 2] = c0;
        attr2[e * 2 + 1] = c1;
        m = fmaxf(fabsf(c0), fabsf(c1));
    }
#pragma unroll
    for (int off = 32; off > 0; off >>= 1) m = fmaxf(m, __shfl_down(m, off));
    if ((threadIdx.x & 63) == 0) atomicMax(scaleb, __float_as_uint(m));
}

__global__ void attr2_fin(float* __restrict__ attr2, const unsigned* __restrict__ scaleb) {
    int gid = blockIdx.x * blockDim.x + threadIdx.x;
    if (gid >= EE2 * 2) return;
    float s = fmaxf(__uint_as_float(*scaleb), 1e-12f);
    attr2[gid] = attr2[gid] / (2.0f * s) + 0.5f;
}

// ---------- conv2: W2 staged in LDS, f split into 4 quarters ----------
// LDS layout: float4 chunks indexed [slot(25)][g(8)][fh(16)] where the float4
// covers fin = 4g..4g+3 at fout = q*16+fh. 25*8*16*16B = 50KB.

__global__ __launch_bounds__(256) void conv2_lds(const float* __restrict__ x1,
                                                 const float* __restrict__ attr2,
                                                 const int* __restrict__ ei2,
                                                 const float* __restrict__ W2,
                                                 float* __restrict__ agg2,
                                                 float* __restrict__ cnt2) {
    __shared__ float wl[25 * 8 * FH * 4];
    const int q = blockIdx.x & 3;
    const int blk = blockIdx.x >> 2;
    const int t = threadIdx.x;

    // stage W2 quarter
    for (int i = t; i < 25 * 8 * FH * 4; i += 256) {
        int c = i & 3;
        int fh = (i >> 2) & (FH - 1);
        int g = (i >> 6) & 7;
        int s = i >> 9;
        wl[i] = W2[s * 2048 + (g * 4 + c) * 64 + q * FH + fh];
    }
    __syncthreads();

    const int fh = t & (FH - 1);
    const int grp = t >> 4;  // 16 groups
    const int EPB = (EE2 + NBLK - 1) / NBLK;  // 352
    const int e0 = blk * EPB;
    const int e_end = min(e0 + EPB, EE2);
    const float4* wl4 = (const float4*)wl;

    for (int e = e0 + grp; e < e_end; e += 16) {
        int src = ei2[e], dst = ei2[EE2 + e];
        int idx[4]; float w[4];
        spline_basis(attr2[2 * e], attr2[2 * e + 1], idx, w);
        const float4* xp = (const float4*)(x1 + src * 32);
        float4 xv[8];
#pragma unroll
        for (int g = 0; g < 8; ++g) xv[g] = xp[g];
        float msg = 0.0f;
#pragma unroll
        for (int k = 0; k < 4; ++k) {
            const float4* wp = wl4 + idx[k] * (8 * FH) + fh;
            float acc = 0.0f;
#pragma unroll
            for (int g = 0; g < 8; ++g) {
                float4 wv = wp[g * FH];
                acc += xv[g].x * wv.x;
                acc += xv[g].y * wv.y;
                acc += xv[g].z * wv.z;
                acc += xv[g].w * wv.w;
            }
            msg += w[k] * acc;
        }
        atomicAdd(&agg2[dst * 64 + q * FH + fh], msg);
        if (q == 0 && fh == 0) atomicAdd(&cnt2[dst], 1.0f);
    }
}

__global__ void conv2_fin(const float* __restrict__ x1, const float* __restrict__ root2,
                          const float* __restrict__ bias2, const float* __restrict__ cnt2,
                          float* __restrict__ agg2) {
    int gid = blockIdx.x * blockDim.x + threadIdx.x;
    if (gid >= NP1 * 64) return;
    int n = gid >> 6, f = gid & 63;
    float r = 0.0f;
    const float* xs = x1 + n * 32;
#pragma unroll
    for (int i = 0; i < 32; ++i) r += xs[i] * root2[i * 64 + f];
    float v = agg2[gid] / fmaxf(cnt2[n], 1.0f) + r + bias2[f];
    agg2[gid] = elu1(v);
}

// ---------- pool2 + global pool ----------

__global__ void pool2(const float* __restrict__ h2, const int* __restrict__ batch1,
                      const int* __restrict__ cl2, unsigned* __restrict__ x2key,
                      int* __restrict__ ccnt2, int* __restrict__ batch2) {
    int gid = blockIdx.x * blockDim.x + threadIdx.x;
    if (gid >= NP1 * 64) return;
    int n = gid >> 6, f = gid & 63;
    int c = cl2[n];
    atomicMax(&x2key[c * 64 + f], fkey(h2[gid]));
    if (f == 0) {
        atomicAdd(&ccnt2[c], 1);
        atomicMax(&batch2[c], batch1[n]);
    }
}

__global__ void pool2_fin(const unsigned* __restrict__ x2key, const int* __restrict__ ccnt2,
                          const int* __restrict__ batch2, float* __restrict__ gsum,
                          float* __restrict__ gcnt) {
    int gid = blockIdx.x * blockDim.x + threadIdx.x;
    if (gid >= NP2 * 64) return;
    int c = gid >> 6, f = gid & 63;
    int cnt = ccnt2[c];
    float v = cnt > 0 ? fkey_inv(x2key[gid]) : 0.0f;
    int g = batch2[c];
    atomicAdd(&gsum[g * 64 + f], v);
    if (f == 0) atomicAdd(&gcnt[g], 1.0f);
}

// ---------- head ----------

__global__ void head_k(const float* __restrict__ gsum, const float* __restrict__ gcnt,
                       const float* __restrict__ fc1w, const float* __restrict__ fc1b,
                       const float* __restrict__ fc2w, const float* __restrict__ fc2b,
                       float* __restrict__ out) {
    int g = blockIdx.x;
    int t = threadIdx.x;
    __shared__ float gm[64];
    __shared__ float h3[128];
    __shared__ float lg[3];
    if (t < 64) gm[t] = gsum[g * 64 + t] / fmaxf(gcnt[g], 1.0f);
    __syncthreads();
    float a = fc1b[t];
#pragma unroll
    for (int i = 0; i < 64; ++i) a += gm[i] * fc1w[i * 128 + t];
    h3[t] = elu1(a);
    __syncthreads();
    if (t < 3) {
        float a2 = fc2b[t];
#pragma unroll
        for (int i = 0; i < 128; ++i) a2 += h3[i] * fc2w[i * 3 + t];
        lg[t] = a2;
    }
    __syncthreads();
    if (t == 0) {
        float m = fmaxf(lg[0], fmaxf(lg[1], lg[2]));
        float s = expf(lg[0] - m) + expf(lg[1] - m) + expf(lg[2] - m);
        float lse = m + logf(s);
        out[g * 3 + 0] = lg[0] - lse;
        out[g * 3 + 1] = lg[1] - lse;
        out[g * 3 + 2] = lg[2] - lse;
    }
}

// ---------- launcher ----------

extern "C" void kernel_launch(void* const* d_in, const int* in_sizes, int n_in,
                              void* d_out, int out_size, void* d_ws, size_t ws_size,
                              hipStream_t stream) {
    const float* x     = (const float*)d_in[0];
    const float* pos   = (const float*)d_in[1];
    const float* eattr = (const float*)d_in[2];
    const int*   ei    = (const int*)d_in[3];
    const int*   batch = (const int*)d_in[4];
    const int*   cl1   = (const int*)d_in[5];
    const int*   ei2   = (const int*)d_in[6];
    const int*   cl2   = (const int*)d_in[7];
    const float* W1    = (const float*)d_in[8];
    const float* root1 = (const float*)d_in[9];
    const float* bias1 = (const float*)d_in[10];
    const float* W2    = (const float*)d_in[11];
    const float* root2 = (const float*)d_in[12];
    const float* bias2 = (const float*)d_in[13];
    const float* fc1w  = (const float*)d_in[14];
    const float* fc1b  = (const float*)d_in[15];
    const float* fc2w  = (const float*)d_in[16];
    const float* fc2b  = (const float*)d_in[17];
    float* out = (float*)d_out;

    char* p = (char*)d_ws;
    auto carve = [&](size_t bytes) {
        char* r = p;
        p += (bytes + 255) & ~(size_t)255;
        return r;
    };
    float*    agg1   = (float*)carve((size_t)NN * 32 * 4);
    float*    cnt1   = (float*)carve((size_t)NN * 4);
    unsigned* x1key  = (unsigned*)carve((size_t)NP1 * 32 * 4);  // becomes float x1 in-place
    int*      ccnt1  = (int*)carve((size_t)NP1 * 4);
    float*    pos1   = (float*)carve((size_t)NP1 * 2 * 4);
    int*      batch1 = (int*)carve((size_t)NP1 * 4);
    unsigned* scaleb = (unsigned*)carve(4);
    float*    attr2  = (float*)carve((size_t)EE2 * 2 * 4);
    float*    agg2   = (float*)carve((size_t)NP1 * 64 * 4);
    float*    cnt2   = (float*)carve((size_t)NP1 * 4);
    unsigned* x2key  = (unsigned*)carve((size_t)NP2 * 64 * 4);
    int*      ccnt2  = (int*)carve((size_t)NP2 * 4);
    int*      batch2 = (int*)carve((size_t)NP2 * 4);
    float*    gsum   = (float*)carve((size_t)GG * 64 * 4);
    float*    gcnt   = (float*)carve((size_t)GG * 4);
    size_t used = (size_t)(p - (char*)d_ws);
    hipMemsetAsync(d_ws, 0, used, stream);

    const int B = 256;
    conv1_edge<<<(EE * 32 + B - 1) / B, B, 0, stream>>>(x, eattr, ei, W1, agg1, cnt1);
    conv1_fin<<<(NN * 32 + B - 1) / B, B, 0, stream>>>(x, root1, bias1, cnt1, agg1);
    pool1<<<(NN * 32 + B - 1) / B, B, 0, stream>>>(agg1, pos, batch, cl1, x1key, ccnt1, pos1, batch1);
    pool1_fin<<<(NP1 * 32 + B - 1) / B, B, 0, stream>>>(x1key, ccnt1, pos1);
    cart_k<<<(EE2 + B - 1) / B, B, 0, stream>>>(pos1, ei2, attr2, scaleb);
    attr2_fin<<<(EE2 * 2 + B - 1) / B, B, 0, stream>>>(attr2, scaleb);
    conv2_lds<<<NBLK * 4, 256, 0, stream>>>((const float*)x1key, attr2, ei2, W2, agg2, cnt2);
    conv2_fin<<<(NP1 * 64 + B - 1) / B, B, 0, stream>>>((const float*)x1key, root2, bias2, cnt2, agg2);
    pool2<<<(NP1 * 64 + B - 1) / B, B, 0, stream>>>(agg2, batch1, cl2, x2key, ccnt2, batch2);
    pool2_fin<<<(NP2 * 64 + B - 1) / B, B, 0, stream>>>(x2key, ccnt2, batch2, gsum, gcnt);
    head_k<<<GG, 128, 0, stream>>>(gsum, gcnt, fc1w, fc1b, fc2w, fc2b, out);
}

// Round 3
// 278.521 us; speedup vs baseline: 1.8416x; 1.3217x over previous
//
#include <hip/hip_runtime.h>
#include <math.h>

#define KD 5
#define NN 60000
#define EE 360000
#define NP1 30000
#define EE2 180000
#define NP2 15000
#define GG 60

// conv2 tiling
#define FH 16      // fout quarter width
#define NBLK 512   // edge blocks per quarter

// pool2/global-pool partials
#define PB2 120
#define CPB2 125   // ceil(NP2 / PB2)

// ---------- helpers ----------

__device__ __forceinline__ unsigned fkey(float f) {
    unsigned u = __float_as_uint(f);
    return (u & 0x80000000u) ? ~u : (u | 0x80000000u);
}
__device__ __forceinline__ float fkey_inv(unsigned k) {
    unsigned u = (k & 0x80000000u) ? (k ^ 0x80000000u) : ~k;
    return __uint_as_float(u);
}

__device__ __forceinline__ void spline_basis(float p0, float p1, int* idx, float* w) {
    float v0 = p0 * 4.0f, v1 = p1 * 4.0f;
    float fl0 = floorf(v0), fl1 = floorf(v1);
    int i0 = min(max((int)fl0, 0), KD - 1);
    int i1 = min(max((int)fl1, 0), KD - 1);
    float fr0 = v0 - fl0, fr1 = v1 - fl1;
    int c = 0;
#pragma unroll
    for (int s0 = 0; s0 < 2; ++s0) {
#pragma unroll
        for (int s1 = 0; s1 < 2; ++s1) {
            int ix = min(i0 + s0, KD - 1);
            int iy = min(i1 + s1, KD - 1);
            float w0 = s0 ? fr0 : 1.0f - fr0;
            float w1 = s1 ? fr1 : 1.0f - fr1;
            idx[c] = ix + KD * iy;
            w[c] = w0 * w1;
            ++c;
        }
    }
}

__device__ __forceinline__ float elu1(float v) {
    return v > 0.0f ? v : expm1f(v);
}

// ---------- conv1 ----------

__global__ void conv1_edge(const float* __restrict__ x, const float* __restrict__ ea,
                           const int* __restrict__ ei, const float* __restrict__ W1,
                           float* __restrict__ agg1, float* __restrict__ cnt1) {
    int gid = blockIdx.x * blockDim.x + threadIdx.x;
    if (gid >= EE * 32) return;
    int e = gid >> 5, f = gid & 31;
    int src = ei[e], dst = ei[EE + e];
    int idx[4]; float w[4];
    spline_basis(ea[2 * e], ea[2 * e + 1], idx, w);
    float coeff = 0.0f;
#pragma unroll
    for (int k = 0; k < 4; ++k) coeff += w[k] * W1[idx[k] * 32 + f];
    atomicAdd(&agg1[dst * 32 + f], x[src] * coeff);
    if (f == 0) atomicAdd(&cnt1[dst], 1.0f);
}

__global__ void conv1_fin(const float* __restrict__ x, const float* __restrict__ root1,
                          const float* __restrict__ bias1, const float* __restrict__ cnt1,
                          float* __restrict__ agg1) {
    int gid = blockIdx.x * blockDim.x + threadIdx.x;
    if (gid >= NN * 32) return;
    int n = gid >> 5, f = gid & 31;
    float v = agg1[gid] / fmaxf(cnt1[n], 1.0f) + x[n] * root1[f] + bias1[f];
    agg1[gid] = elu1(v);
}

// ---------- pool1 ----------

__global__ void pool1(const float* __restrict__ h, const float* __restrict__ pos,
                      const int* __restrict__ batch, const int* __restrict__ cl1,
                      unsigned* __restrict__ x1key, int* __restrict__ ccnt1,
                      float* __restrict__ pos1, int* __restrict__ batch1) {
    int gid = blockIdx.x * blockDim.x + threadIdx.x;
    if (gid >= NN * 32) return;
    int n = gid >> 5, f = gid & 31;
    int c = cl1[n];
    atomicMax(&x1key[c * 32 + f], fkey(h[gid]));
    if (f == 0) {
        atomicAdd(&ccnt1[c], 1);
        atomicAdd(&pos1[c * 2], pos[n * 2]);
        atomicAdd(&pos1[c * 2 + 1], pos[n * 2 + 1]);
        atomicMax(&batch1[c], batch[n]);
    }
}

__global__ void pool1_fin(unsigned* __restrict__ x1key, const int* __restrict__ ccnt1,
                          float* __restrict__ pos1) {
    int gid = blockIdx.x * blockDim.x + threadIdx.x;
    if (gid >= NP1 * 32) return;
    int c = gid >> 5, f = gid & 31;
    int cnt = ccnt1[c];
    float v = cnt > 0 ? fkey_inv(x1key[gid]) : 0.0f;
    ((float*)x1key)[gid] = v;
    if (f < 2) pos1[c * 2 + f] = pos1[c * 2 + f] / fmaxf((float)cnt, 1.0f);
}

// ---------- cartesian ----------

__global__ void cart_k(const float* __restrict__ pos1, const int* __restrict__ ei2,
                       float* __restrict__ attr2, unsigned* __restrict__ scaleb) {
    int e = blockIdx.x * blockDim.x + threadIdx.x;
    float m = 0.0f;
    if (e < EE2) {
        int s = ei2[e], d = ei2[EE2 + e];
        float c0 = pos1[d * 2] - pos1[s * 2];
        float c1 = pos1[d * 2 + 1] - pos1[s * 2 + 1];
        attr2[e * 2] = c0;
        attr2[e * 2 + 1] = c1;
        m = fmaxf(fabsf(c0), fabsf(c1));
    }
#pragma unroll
    for (int off = 32; off > 0; off >>= 1) m = fmaxf(m, __shfl_down(m, off));
    if ((threadIdx.x & 63) == 0) atomicMax(scaleb, __float_as_uint(m));
}

__global__ void attr2_fin(float* __restrict__ attr2, const unsigned* __restrict__ scaleb) {
    int gid = blockIdx.x * blockDim.x + threadIdx.x;
    if (gid >= EE2 * 2) return;
    float s = fmaxf(__uint_as_float(*scaleb), 1e-12f);
    attr2[gid] = attr2[gid] / (2.0f * s) + 0.5f;
}

// ---------- conv2: W2 staged in LDS, f split into 4 quarters ----------

__global__ __launch_bounds__(256) void conv2_lds(const float* __restrict__ x1,
                                                 const float* __restrict__ attr2,
                                                 const int* __restrict__ ei2,
                                                 const float* __restrict__ W2,
                                                 float* __restrict__ agg2,
                                                 float* __restrict__ cnt2) {
    __shared__ float wl[25 * 8 * FH * 4];
    const int q = blockIdx.x & 3;
    const int blk = blockIdx.x >> 2;
    const int t = threadIdx.x;

    for (int i = t; i < 25 * 8 * FH * 4; i += 256) {
        int c = i & 3;
        int fh = (i >> 2) & (FH - 1);
        int g = (i >> 6) & 7;
        int s = i >> 9;
        wl[i] = W2[s * 2048 + (g * 4 + c) * 64 + q * FH + fh];
    }
    __syncthreads();

    const int fh = t & (FH - 1);
    const int grp = t >> 4;
    const int EPB = (EE2 + NBLK - 1) / NBLK;
    const int e0 = blk * EPB;
    const int e_end = min(e0 + EPB, EE2);
    const float4* wl4 = (const float4*)wl;

    for (int e = e0 + grp; e < e_end; e += 16) {
        int src = ei2[e], dst = ei2[EE2 + e];
        int idx[4]; float w[4];
        spline_basis(attr2[2 * e], attr2[2 * e + 1], idx, w);
        const float4* xp = (const float4*)(x1 + src * 32);
        float4 xv[8];
#pragma unroll
        for (int g = 0; g < 8; ++g) xv[g] = xp[g];
        float msg = 0.0f;
#pragma unroll
        for (int k = 0; k < 4; ++k) {
            const float4* wp = wl4 + idx[k] * (8 * FH) + fh;
            float acc = 0.0f;
#pragma unroll
            for (int g = 0; g < 8; ++g) {
                float4 wv = wp[g * FH];
                acc += xv[g].x * wv.x;
                acc += xv[g].y * wv.y;
                acc += xv[g].z * wv.z;
                acc += xv[g].w * wv.w;
            }
            msg += w[k] * acc;
        }
        atomicAdd(&agg2[dst * 64 + q * FH + fh], msg);
        if (q == 0 && fh == 0) atomicAdd(&cnt2[dst], 1.0f);
    }
}

__global__ void conv2_fin(const float* __restrict__ x1, const float* __restrict__ root2,
                          const float* __restrict__ bias2, const float* __restrict__ cnt2,
                          float* __restrict__ agg2) {
    int gid = blockIdx.x * blockDim.x + threadIdx.x;
    if (gid >= NP1 * 64) return;
    int n = gid >> 6, f = gid & 63;
    float r = 0.0f;
    const float* xs = x1 + n * 32;
#pragma unroll
    for (int i = 0; i < 32; ++i) r += xs[i] * root2[i * 64 + f];
    float v = agg2[gid] / fmaxf(cnt2[n], 1.0f) + r + bias2[f];
    agg2[gid] = elu1(v);
}

// ---------- pool2 ----------

__global__ void pool2(const float* __restrict__ h2, const int* __restrict__ batch1,
                      const int* __restrict__ cl2, unsigned* __restrict__ x2key,
                      int* __restrict__ ccnt2, int* __restrict__ batch2) {
    int gid = blockIdx.x * blockDim.x + threadIdx.x;
    if (gid >= NP1 * 64) return;
    int n = gid >> 6, f = gid & 63;
    int c = cl2[n];
    atomicMax(&x2key[c * 64 + f], fkey(h2[gid]));
    if (f == 0) {
        atomicAdd(&ccnt2[c], 1);
        atomicMax(&batch2[c], batch1[n]);
    }
}

// ---------- global mean pool: per-block LDS partials, no global atomics ----------

__global__ __launch_bounds__(256) void pool2_part(const unsigned* __restrict__ x2key,
                                                  const int* __restrict__ ccnt2,
                                                  const int* __restrict__ batch2,
                                                  float* __restrict__ partial,
                                                  float* __restrict__ pcnt) {
    __shared__ float gs[GG * 64 + GG];
    const int t = threadIdx.x;
    for (int i = t; i < GG * 64 + GG; i += 256) gs[i] = 0.0f;
    __syncthreads();
    const int lane = t & 63, wv = t >> 6;
    const int c0 = blockIdx.x * CPB2;
    const int c1 = min(c0 + CPB2, NP2);
    for (int c = c0 + wv; c < c1; c += 4) {
        int cnt = ccnt2[c];
        int g = batch2[c];
        float v = cnt > 0 ? fkey_inv(x2key[c * 64 + lane]) : 0.0f;
        atomicAdd(&gs[g * 64 + lane], v);                 // LDS atomic
        if (lane == 0) atomicAdd(&gs[GG * 64 + g], 1.0f); // LDS atomic
    }
    __syncthreads();
    float* pb = partial + (size_t)blockIdx.x * (GG * 64);
    for (int i = t; i < GG * 64; i += 256) pb[i] = gs[i];
    if (t < GG) pcnt[blockIdx.x * GG + t] = gs[GG * 64 + t];
}

// ---------- fused partial-reduce + head (one block per graph) ----------

__global__ __launch_bounds__(128) void gpool_head(const float* __restrict__ partial,
                                                  const float* __restrict__ pcnt,
                                                  const float* __restrict__ fc1w,
                                                  const float* __restrict__ fc1b,
                                                  const float* __restrict__ fc2w,
                                                  const float* __restrict__ fc2b,
                                                  float* __restrict__ out) {
    const int g = blockIdx.x;
    const int t = threadIdx.x;  // 128
    __shared__ float red[128];
    __shared__ float acc2[128];
    __shared__ float gm[64];
    __shared__ float h3[128];
    __shared__ float lg[3];

    // graph count = sum of per-block partial counts
    red[t] = (t < PB2) ? pcnt[t * GG + g] : 0.0f;
    __syncthreads();
    for (int s = 64; s > 0; s >>= 1) {
        if (t < s) red[t] += red[t + s];
        __syncthreads();
    }

    // feature sums: thread t handles f = t&63, half = t>>6 of the block range
    const int f = t & 63, h = t >> 6;
    float acc = 0.0f;
    for (int b = h * (PB2 / 2); b < (h + 1) * (PB2 / 2); ++b)
        acc += partial[(size_t)b * (GG * 64) + g * 64 + f];
    acc2[t] = acc;
    __syncthreads();
    if (t < 64) gm[t] = (acc2[t] + acc2[t + 64]) / fmaxf(red[0], 1.0f);
    __syncthreads();

    // fc1 + elu
    float a = fc1b[t];
#pragma unroll
    for (int i = 0; i < 64; ++i) a += gm[i] * fc1w[i * 128 + t];
    h3[t] = elu1(a);
    __syncthreads();
    if (t < 3) {
        float a2 = fc2b[t];
#pragma unroll
        for (int i = 0; i < 128; ++i) a2 += h3[i] * fc2w[i * 3 + t];
        lg[t] = a2;
    }
    __syncthreads();
    if (t == 0) {
        float m = fmaxf(lg[0], fmaxf(lg[1], lg[2]));
        float s = expf(lg[0] - m) + expf(lg[1] - m) + expf(lg[2] - m);
        float lse = m + logf(s);
        out[g * 3 + 0] = lg[0] - lse;
        out[g * 3 + 1] = lg[1] - lse;
        out[g * 3 + 2] = lg[2] - lse;
    }
}

// ---------- launcher ----------

extern "C" void kernel_launch(void* const* d_in, const int* in_sizes, int n_in,
                              void* d_out, int out_size, void* d_ws, size_t ws_size,
                              hipStream_t stream) {
    const float* x     = (const float*)d_in[0];
    const float* pos   = (const float*)d_in[1];
    const float* eattr = (const float*)d_in[2];
    const int*   ei    = (const int*)d_in[3];
    const int*   batch = (const int*)d_in[4];
    const int*   cl1   = (const int*)d_in[5];
    const int*   ei2   = (const int*)d_in[6];
    const int*   cl2   = (const int*)d_in[7];
    const float* W1    = (const float*)d_in[8];
    const float* root1 = (const float*)d_in[9];
    const float* bias1 = (const float*)d_in[10];
    const float* W2    = (const float*)d_in[11];
    const float* root2 = (const float*)d_in[12];
    const float* bias2 = (const float*)d_in[13];
    const float* fc1w  = (const float*)d_in[14];
    const float* fc1b  = (const float*)d_in[15];
    const float* fc2w  = (const float*)d_in[16];
    const float* fc2b  = (const float*)d_in[17];
    float* out = (float*)d_out;

    char* p = (char*)d_ws;
    auto carve = [&](size_t bytes) {
        char* r = p;
        p += (bytes + 255) & ~(size_t)255;
        return r;
    };
    float*    agg1    = (float*)carve((size_t)NN * 32 * 4);
    float*    cnt1    = (float*)carve((size_t)NN * 4);
    unsigned* x1key   = (unsigned*)carve((size_t)NP1 * 32 * 4);  // becomes float x1 in-place
    int*      ccnt1   = (int*)carve((size_t)NP1 * 4);
    float*    pos1    = (float*)carve((size_t)NP1 * 2 * 4);
    int*      batch1  = (int*)carve((size_t)NP1 * 4);
    unsigned* scaleb  = (unsigned*)carve(4);
    float*    attr2   = (float*)carve((size_t)EE2 * 2 * 4);
    float*    agg2    = (float*)carve((size_t)NP1 * 64 * 4);
    float*    cnt2    = (float*)carve((size_t)NP1 * 4);
    unsigned* x2key   = (unsigned*)carve((size_t)NP2 * 64 * 4);
    int*      ccnt2   = (int*)carve((size_t)NP2 * 4);
    int*      batch2  = (int*)carve((size_t)NP2 * 4);
    float*    partial = (float*)carve((size_t)PB2 * GG * 64 * 4);
    float*    pcnt    = (float*)carve((size_t)PB2 * GG * 4);
    size_t used = (size_t)(p - (char*)d_ws);
    hipMemsetAsync(d_ws, 0, used, stream);

    const int B = 256;
    conv1_edge<<<(EE * 32 + B - 1) / B, B, 0, stream>>>(x, eattr, ei, W1, agg1, cnt1);
    conv1_fin<<<(NN * 32 + B - 1) / B, B, 0, stream>>>(x, root1, bias1, cnt1, agg1);
    pool1<<<(NN * 32 + B - 1) / B, B, 0, stream>>>(agg1, pos, batch, cl1, x1key, ccnt1, pos1, batch1);
    pool1_fin<<<(NP1 * 32 + B - 1) / B, B, 0, stream>>>(x1key, ccnt1, pos1);
    cart_k<<<(EE2 + B - 1) / B, B, 0, stream>>>(pos1, ei2, attr2, scaleb);
    attr2_fin<<<(EE2 * 2 + B - 1) / B, B, 0, stream>>>(attr2, scaleb);
    conv2_lds<<<NBLK * 4, 256, 0, stream>>>((const float*)x1key, attr2, ei2, W2, agg2, cnt2);
    conv2_fin<<<(NP1 * 64 + B - 1) / B, B, 0, stream>>>((const float*)x1key, root2, bias2, cnt2, agg2);
    pool2<<<(NP1 * 64 + B - 1) / B, B, 0, stream>>>(agg2, batch1, cl2, x2key, ccnt2, batch2);
    pool2_part<<<PB2, 256, 0, stream>>>(x2key, ccnt2, batch2, partial, pcnt);
    gpool_head<<<GG, 128, 0, stream>>>(partial, pcnt, fc1w, fc1b, fc2w, fc2b, out);
}